// Round 5
// baseline (1191.363 us; speedup 1.0000x reference)
//
#include <hip/hip_runtime.h>
#include <hip/hip_fp16.h>
#include <math.h>

#define NN 100000
#define NE 1600000
#define NB ((NN + 255) >> 8)   // 391 buckets of 256 nodes
#define CHUNK 8192
#define CAP 8192

typedef __attribute__((ext_vector_type(4))) float floatx4;
typedef __attribute__((ext_vector_type(8))) short shortx8;

// ---------------- bucketed CSR build ----------------

__global__ __launch_bounds__(256)
void coarse_hist(const int* __restrict__ ei, int* __restrict__ bucket_cnt, int E) {
    __shared__ int h[512];
    int t = threadIdx.x;
    for (int i = t; i < 512; i += 256) h[i] = 0;
    __syncthreads();
    int base = blockIdx.x * CHUNK;
    int lim = min(base + CHUNK, E);
    for (int e = base + t; e < lim; e += 256) {
        int d = ei[E + e];
        atomicAdd(&h[d >> 8], 1);
    }
    __syncthreads();
    for (int i = t; i < 512; i += 256)
        if (h[i]) atomicAdd(&bucket_cnt[i], h[i]);
}

__global__ void scan_buckets(const int* __restrict__ bucket_cnt,
                             int* __restrict__ bucket_base,
                             int* __restrict__ bucket_fill) {
    __shared__ int sh[512];
    int t = threadIdx.x;  // 512 threads
    int v = (t < NB) ? bucket_cnt[t] : 0;
    sh[t] = v;
    __syncthreads();
    for (int off = 1; off < 512; off <<= 1) {
        int u = (t >= off) ? sh[t - off] : 0;
        __syncthreads();
        sh[t] += u;
        __syncthreads();
    }
    int ex = (t == 0) ? 0 : sh[t - 1];
    if (t <= NB) bucket_base[t] = ex;
    if (t < NB) bucket_fill[t] = ex;
}

__global__ __launch_bounds__(256)
void coarse_scatter(const int* __restrict__ ei, int* __restrict__ bucket_fill,
                    unsigned long long* __restrict__ pairs, int E) {
    __shared__ int h[512];
    __shared__ int base[512];
    int t = threadIdx.x;
    for (int i = t; i < 512; i += 256) h[i] = 0;
    __syncthreads();
    int cbase = blockIdx.x * CHUNK;
    int lim = min(cbase + CHUNK, E);
    for (int e = cbase + t; e < lim; e += 256) {
        int d = ei[E + e];
        atomicAdd(&h[d >> 8], 1);
    }
    __syncthreads();
    for (int i = t; i < 512; i += 256)
        base[i] = h[i] ? atomicAdd(&bucket_fill[i], h[i]) : 0;
    __syncthreads();
    for (int i = t; i < 512; i += 256) h[i] = 0;
    __syncthreads();
    for (int e = cbase + t; e < lim; e += 256) {
        int s = ei[e];
        int d = ei[E + e];
        int b = d >> 8;
        int r = atomicAdd(&h[b], 1);
        pairs[base[b] + r] =
            ((unsigned long long)(unsigned)d << 32) | (unsigned)s;
    }
}

__global__ __launch_bounds__(256)
void fine_csr(const unsigned long long* __restrict__ pairs,
              const int* __restrict__ bucket_base,
              int* __restrict__ rowptr, int* __restrict__ colid,
              float* __restrict__ dinv, int n) {
    __shared__ int hist[256];
    __shared__ int offs[256];
    __shared__ int rank[256];
    __shared__ int lbuf[CAP];
    int b = blockIdx.x, t = threadIdx.x;
    int beg = bucket_base[b], end = bucket_base[b + 1];
    int cnt = end - beg;
    hist[t] = 0; rank[t] = 0;
    __syncthreads();
    for (int i = t; i < cnt; i += 256) {
        int d = (int)(pairs[beg + i] >> 32);
        atomicAdd(&hist[d & 255], 1);
    }
    __syncthreads();
    int v = hist[t];
    offs[t] = v;
    __syncthreads();
    for (int off = 1; off < 256; off <<= 1) {
        int u = (t >= off) ? offs[t - off] : 0;
        __syncthreads();
        offs[t] += u;
        __syncthreads();
    }
    int ex = (t == 0) ? 0 : offs[t - 1];
    int node = (b << 8) + t;
    if (node < n) {
        rowptr[node] = beg + ex;
        dinv[node] = rsqrtf((float)v + 1.0f);
    } else if (node == n) {
        rowptr[n] = beg + ex;
    }
    __syncthreads();
    offs[t] = ex;
    __syncthreads();
    for (int i = t; i < cnt; i += 256) {
        unsigned long long p = pairs[beg + i];
        int d = (int)(p >> 32) & 255;
        int s = (int)(p & 0xffffffffu);
        int r = atomicAdd(&rank[d], 1);
        lbuf[offs[d] + r] = s;
    }
    __syncthreads();
    for (int i = t; i < cnt; i += 256) colid[beg + i] = lbuf[i];
}

// ---------------- weight prep: W[K][OUT] fp32 -> swizzled bf16 hi/lo fragments ----
// all 6 layers in ONE launch (segment dispatch on flat index).

__device__ __forceinline__ void wsplit_one(const float* __restrict__ W,
                                           unsigned short* __restrict__ Wsw,
                                           int i, int K, int OUT) {
    int k = i / OUT, o = i % OUT;
    float w = W[i];
    unsigned u = __float_as_uint(w);
    float r = w - __uint_as_float(u & 0xFFFF0000u);
    int NT = OUT >> 4;
    int ktc = k >> 5, q = (k >> 3) & 3, j = k & 7;
    int nt = o >> 4, mm = o & 15;
    int lane = (q << 4) | mm;
    size_t base = ((((size_t)(ktc * NT + nt) * 2) * 64 + lane) << 3) + j;
    Wsw[base] = (unsigned short)(u >> 16);
    Wsw[base + 512] = (unsigned short)(__float_as_uint(r) >> 16);  // h=1: +64*8
}

__global__ __launch_bounds__(256)
void wsplit_all(const float* __restrict__ W0, unsigned short* __restrict__ O0,
                const float* __restrict__ W1, unsigned short* __restrict__ O1,
                const float* __restrict__ W2, unsigned short* __restrict__ O2,
                const float* __restrict__ W3, unsigned short* __restrict__ O3,
                const float* __restrict__ W4, unsigned short* __restrict__ O4,
                const float* __restrict__ W5, unsigned short* __restrict__ O5) {
    int i = blockIdx.x * 256 + threadIdx.x;
    // sizes: e1 20480, e2 16384, e3 8192, d1 12288, d2 16384, d3 16384
    if (i < 20480) { wsplit_one(W0, O0, i, 160, 128); return; }
    i -= 20480;
    if (i < 16384) { wsplit_one(W1, O1, i, 128, 128); return; }
    i -= 16384;
    if (i < 8192)  { wsplit_one(W2, O2, i, 128, 64);  return; }
    i -= 8192;
    if (i < 12288) { wsplit_one(W3, O3, i, 96, 128);  return; }
    i -= 12288;
    if (i < 16384) { wsplit_one(W4, O4, i, 128, 128); return; }
    i -= 16384;
    if (i < 16384) { wsplit_one(W5, O5, i, 128, 128); }
}

// ---------------- MFMA GEMM ----------------
// Y16 CHUNK-MAJOR, 16-feature chunks: Y[(nt*n + row)*16 + m] fp16
// (32 B per (node,chunk) unit; chunk slice = 3.2 MB -> fits one XCD L2).
// Two input pointers: columns [0,K1) from X1 (stride K1), [K1,K) from X2 (stride K-K1).

__device__ __forceinline__ void split8(const float* v, shortx8& hi, shortx8& lo) {
#pragma unroll
    for (int i = 0; i < 8; i++) {
        unsigned u = __float_as_uint(v[i]);
        float r = v[i] - __uint_as_float(u & 0xFFFF0000u);
        hi[i] = (short)(u >> 16);
        lo[i] = (short)(__float_as_uint(r) >> 16);
    }
}

template <int OUT, int K, int K1>
__global__ __launch_bounds__(512)
void gemm_mfma(const float* __restrict__ X1, const float* __restrict__ X2,
               const unsigned short* __restrict__ Wsw,
               const float* __restrict__ dinv,
               __half* __restrict__ Y, int ntiles) {
    constexpr int NT = OUT / 16;
    constexpr int NKTC = K / 32;
    constexpr int K2 = K - K1;
    constexpr int PERC = OUT * 128;  // bytes per ktc chunk
    constexpr int CSZ = (65536 / PERC < NKTC) ? (65536 / PERC) : NKTC;
    __shared__ __align__(16) unsigned short lds[CSZ * PERC / 2];

    const int t = threadIdx.x;
    const int wave = t >> 6, lane = t & 63;
    const int m = lane & 15, q = lane >> 4;
    const int tile = blockIdx.x * 8 + wave;
    const bool act = tile < ntiles;
    const int row = act ? tile * 16 + m : 0;
    const int nfull = ntiles * 16;
    const float* ap1 = X1 + (size_t)row * K1 + q * 8;
    const float* ap2 = (K2 > 0) ? (X2 + (size_t)row * K2 + q * 8) : X1;

    floatx4 acc[NT];
#pragma unroll
    for (int nt = 0; nt < NT; nt++) acc[nt] = (floatx4){0.f, 0.f, 0.f, 0.f};

#pragma unroll
    for (int c0 = 0; c0 < NKTC; c0 += CSZ) {
        const int cl = (NKTC - c0 < CSZ) ? (NKTC - c0) : CSZ;
        if (c0 != 0) __syncthreads();
        {
            const float4* gs = (const float4*)Wsw + (size_t)c0 * (PERC / 16);
            float4* ld = (float4*)lds;
            int tot = cl * (PERC / 16);
            for (int i = t; i < tot; i += 512) ld[i] = gs[i];
        }
        __syncthreads();
        if (act) {
#pragma unroll
            for (int ktc = 0; ktc < cl; ktc++) {
                const int kg = (c0 + ktc) * 32;
                const float* p = (kg < K1) ? (ap1 + kg) : (ap2 + (kg - K1));
                float av[8];
                *(float4*)&av[0] = *(const float4*)(p);
                *(float4*)&av[4] = *(const float4*)(p + 4);
                shortx8 ahi, alo;
                split8(av, ahi, alo);
#pragma unroll
                for (int nt = 0; nt < NT; nt++) {
                    const unsigned short* fb =
                        lds + ((((ktc * NT + nt) * 2) * 64 + lane) << 3);
                    shortx8 bhi = *(const shortx8*)fb;
                    shortx8 blo = *(const shortx8*)(fb + 512);
                    acc[nt] = __builtin_amdgcn_mfma_f32_16x16x32_bf16(ahi, bhi, acc[nt], 0, 0, 0);
                    acc[nt] = __builtin_amdgcn_mfma_f32_16x16x32_bf16(ahi, blo, acc[nt], 0, 0, 0);
                    acc[nt] = __builtin_amdgcn_mfma_f32_16x16x32_bf16(alo, bhi, acc[nt], 0, 0, 0);
                }
            }
        }
    }

    if (act) {
        float di[4];
#pragma unroll
        for (int r = 0; r < 4; r++) di[r] = dinv[tile * 16 + q * 4 + r];
#pragma unroll
        for (int nt = 0; nt < NT; nt++) {
#pragma unroll
            for (int r = 0; r < 4; r++) {
                int orow = tile * 16 + q * 4 + r;
                Y[((size_t)nt * nfull + orow) * 16 + m] =
                    __float2half_rn(acc[nt][r] * di[r]);
            }
        }
    }
}

// ---------------- propagation v4: edge-partitioned chunked gather ----------------
// Block = 160 nodes x 1 chunk (16 feats). chunk = bid & (NCH-1): with NCH=8 each
// XCD processes exactly one 3.2 MB chunk slice -> L2-resident (round-1/4 verified
// FETCH at compulsory floor). New vs v3 (which was 110 us, request-rate bound):
//  - 2-lane slots (16 B/lane): ONE gather instruction covers 32 edges (v3: 8)
//    -> scatter-instruction count 2.5M -> ~400K per prop.
//  - edge-partitioned slots: block's CSR-contiguous edge range split evenly into
//    128 slot ranges (uniform trip count -> zero max-of-Poisson divergence).
//    Node-boundary partials flushed to padded LDS accumulator (rare, ~2.3/slot).
//  - colid+rowptr staged in LDS; final pass adds self+bias+tanh, coalesced store.

template <int NCH, bool TANH>
__global__ __launch_bounds__(256)
void prop_ep(const __half2* __restrict__ hs, const float* __restrict__ dinv,
             const int* __restrict__ rowptr, const int* __restrict__ colid,
             const float* __restrict__ bias, float* __restrict__ out,
             int ldo, int n) {
    constexpr int NPB = 160;     // nodes per block (n % 160 == 0 -> 625 blocks)
    constexpr int LCAP = 3072;   // 12 KB; cnt ~ Binom mean 2560 sd 50 (+10sd safe)
    __shared__ float sacc[NPB][17];      // padded: bank = (node + feat) % 32
    __shared__ int lcol[LCAP];
    __shared__ int srow[NPB + 1];

    const int bid = blockIdx.x;
    const int c = bid & (NCH - 1);
    const int nb = bid / NCH;
    const int t = threadIdx.x;
    const int n0 = nb * NPB;

    const int blockBeg = rowptr[n0];
    for (int i = t; i <= NPB; i += 256) srow[i] = rowptr[n0 + i] - blockBeg;
    for (int i = t; i < NPB * 17; i += 256) ((float*)sacc)[i] = 0.f;
    __syncthreads();
    const int cnt = srow[NPB];
    const bool inL = (cnt <= LCAP);
    if (inL) {
        for (int i = t; i < cnt; i += 256)
            lcol[i] = __builtin_nontemporal_load(colid + blockBeg + i);
    }
    __syncthreads();

    {
        const int slot = t >> 1, r = t & 1;         // 128 slots x 2 lanes
        const int sbeg = (cnt * slot) >> 7;
        const int send = (cnt * (slot + 1)) >> 7;
        const float4* __restrict__ base4 =
            (const float4*)hs + (size_t)c * (size_t)n * 2;

        // largest cur with srow[cur] <= sbeg  (branchless binary search)
        int lo = 0, hi = NPB;
#pragma unroll
        for (int it = 0; it < 8; it++) {
            int mid = (lo + hi) >> 1;
            bool le = (srow[mid] <= sbeg);
            lo = le ? mid : lo;
            hi = le ? hi : mid;
        }
        int cur = lo;
        int nxt = srow[cur + 1];
        float a0 = 0, a1 = 0, a2 = 0, a3 = 0, a4 = 0, a5 = 0, a6 = 0, a7 = 0;

        for (int e = sbeg; e < send; e++) {
            if (e >= nxt) {   // node boundary: flush partial, advance (skips empties)
                float* ap = &sacc[cur][r * 8];
                atomicAdd(ap + 0, a0); atomicAdd(ap + 1, a1);
                atomicAdd(ap + 2, a2); atomicAdd(ap + 3, a3);
                atomicAdd(ap + 4, a4); atomicAdd(ap + 5, a5);
                atomicAdd(ap + 6, a6); atomicAdd(ap + 7, a7);
                a0 = a1 = a2 = a3 = a4 = a5 = a6 = a7 = 0.f;
                do { cur++; nxt = srow[cur + 1]; } while (nxt <= e);
            }
            int s = inL ? lcol[e] : colid[blockBeg + e];
            float4 v = base4[(size_t)s * 2 + r];
            const __half2* h = (const __half2*)&v;
            float2 f0 = __half22float2(h[0]); a0 += f0.x; a1 += f0.y;
            float2 f1 = __half22float2(h[1]); a2 += f1.x; a3 += f1.y;
            float2 f2 = __half22float2(h[2]); a4 += f2.x; a5 += f2.y;
            float2 f3 = __half22float2(h[3]); a6 += f3.x; a7 += f3.y;
        }
        if (sbeg < send) {
            float* ap = &sacc[cur][r * 8];
            atomicAdd(ap + 0, a0); atomicAdd(ap + 1, a1);
            atomicAdd(ap + 2, a2); atomicAdd(ap + 3, a3);
            atomicAdd(ap + 4, a4); atomicAdd(ap + 5, a5);
            atomicAdd(ap + 6, a6); atomicAdd(ap + 7, a7);
        }
    }
    __syncthreads();

    // finalize: self-loop + bias (+tanh), coalesced store
    const __half2* __restrict__ hb2 = hs + ((size_t)c * n + n0) * 8;
    for (int i = t; i < NPB * 8; i += 256) {
        int nl = i >> 3, k = i & 7;
        int node = n0 + nl;
        float2 sv = __half22float2(hb2[nl * 8 + k]);
        float di = dinv[node];
        float ox = di * (sacc[nl][2 * k] + sv.x) + bias[c * 16 + 2 * k];
        float oy = di * (sacc[nl][2 * k + 1] + sv.y) + bias[c * 16 + 2 * k + 1];
        if (TANH) { ox = tanhf(ox); oy = tanhf(oy); }
        *(float2*)(out + (size_t)node * ldo + c * 16 + 2 * k) = make_float2(ox, oy);
    }
}

// ---------------- launch ----------------

extern "C" void kernel_launch(void* const* d_in, const int* in_sizes, int n_in,
                              void* d_out, int out_size, void* d_ws, size_t ws_size,
                              hipStream_t stream) {
    const int n = NN, E = NE;
    const float* feature   = (const float*)d_in[0];
    const float* condition = (const float*)d_in[1];
    const int*   ei        = (const int*)d_in[2];
    const float* W_e1 = (const float*)d_in[3];  const float* b_e1 = (const float*)d_in[4];
    const float* W_e2 = (const float*)d_in[5];  const float* b_e2 = (const float*)d_in[6];
    const float* W_e3 = (const float*)d_in[7];  const float* b_e3 = (const float*)d_in[8];
    const float* W_d1 = (const float*)d_in[9];  const float* b_d1 = (const float*)d_in[10];
    const float* W_d2 = (const float*)d_in[11]; const float* b_d2 = (const float*)d_in[12];
    const float* W_d3 = (const float*)d_in[13]; const float* b_d3 = (const float*)d_in[14];
    float* out = (float*)d_out;

    float*  A    = (float*)d_ws;                    // n*160 floats
    __half* H16  = (__half*)(A + (size_t)n * 160);  // n*128 halves
    float*  dinv = (float*)(H16 + (size_t)n * 128); // n
    int* rowptr  = (int*)(dinv + n);                // n+1
    int* colid   = rowptr + n + 1;                  // E
    uintptr_t pp = (uintptr_t)(colid + E);
    pp = (pp + 15) & ~(uintptr_t)15;
    unsigned long long* pairs = (unsigned long long*)pp;  // E
    int* bucket_cnt  = (int*)(pairs + E);           // 512
    int* bucket_base = bucket_cnt + 512;            // 512
    int* bucket_fill = bucket_base + 512;           // 512
    uintptr_t wp = (uintptr_t)(bucket_fill + 512);
    wp = (wp + 15) & ~(uintptr_t)15;
    unsigned short* wt = (unsigned short*)wp;
    unsigned short* e1w = wt;              unsigned short* e2w = e1w + 160 * 128 * 2;
    unsigned short* e3w = e2w + 128*128*2; unsigned short* d1w = e3w + 128 * 64 * 2;
    unsigned short* d2w = d1w + 96*128*2;  unsigned short* d3w = d2w + 128 * 128 * 2;

    hipMemsetAsync(bucket_cnt, 0, 512 * sizeof(int), stream);

    int nbc = (E + CHUNK - 1) / CHUNK;
    coarse_hist<<<nbc, 256, 0, stream>>>(ei, bucket_cnt, E);
    scan_buckets<<<1, 512, 0, stream>>>(bucket_cnt, bucket_base, bucket_fill);
    coarse_scatter<<<nbc, 256, 0, stream>>>(ei, bucket_fill, pairs, E);
    fine_csr<<<NB, 256, 0, stream>>>(pairs, bucket_base, rowptr, colid, dinv, n);

    wsplit_all<<<(90112 + 255) / 256, 256, 0, stream>>>(
        W_e1, e1w, W_e2, e2w, W_e3, e3w, W_d1, d1w, W_d2, d2w, W_d3, d3w);

    const int ntiles = n / 16;          // 6250 exactly
    const int gb = (ntiles + 7) / 8;    // 8 waves per block
    const int eblk = n / 160;           // 625 node-blocks (160 nodes/block)

    // encoder (e1 reads feature+condition directly; no concat)
    gemm_mfma<128, 160, 128><<<gb, 512, 0, stream>>>(feature, condition, e1w, dinv, H16, ntiles);
    prop_ep<8, true><<<8 * eblk, 256, 0, stream>>>((const __half2*)H16, dinv, rowptr, colid, b_e1, A, 128, n);
    gemm_mfma<128, 128, 128><<<gb, 512, 0, stream>>>(A, nullptr, e2w, dinv, H16, ntiles);
    prop_ep<8, true><<<8 * eblk, 256, 0, stream>>>((const __half2*)H16, dinv, rowptr, colid, b_e2, A, 128, n);
    gemm_mfma<64, 128, 128><<<gb, 512, 0, stream>>>(A, nullptr, e3w, dinv, H16, ntiles);
    prop_ep<4, false><<<4 * eblk, 256, 0, stream>>>((const __half2*)H16, dinv, rowptr, colid, b_e3, A, 64, n);

    // decoder (d1 reads z (ld=64) + condition directly; no condcopy)
    gemm_mfma<128, 96, 64><<<gb, 512, 0, stream>>>(A, condition, d1w, dinv, H16, ntiles);
    prop_ep<8, true><<<8 * eblk, 256, 0, stream>>>((const __half2*)H16, dinv, rowptr, colid, b_d1, A, 128, n);
    gemm_mfma<128, 128, 128><<<gb, 512, 0, stream>>>(A, nullptr, d2w, dinv, H16, ntiles);
    prop_ep<8, true><<<8 * eblk, 256, 0, stream>>>((const __half2*)H16, dinv, rowptr, colid, b_d2, A, 128, n);
    gemm_mfma<128, 128, 128><<<gb, 512, 0, stream>>>(A, nullptr, d3w, dinv, H16, ntiles);
    prop_ep<8, false><<<8 * eblk, 256, 0, stream>>>((const __half2*)H16, dinv, rowptr, colid, b_d3, out, 128, n);
}

// Round 6
// 725.136 us; speedup vs baseline: 1.6430x; 1.6430x over previous
//
#include <hip/hip_runtime.h>
#include <hip/hip_fp16.h>
#include <math.h>

#define NN 100000
#define NE 1600000
#define NB ((NN + 255) >> 8)   // 391 buckets of 256 nodes
#define CHUNK 8192
#define CAP 8192

typedef __attribute__((ext_vector_type(4))) float floatx4;
typedef __attribute__((ext_vector_type(8))) short shortx8;

// ---------------- bucketed CSR build ----------------

__global__ __launch_bounds__(256)
void coarse_hist(const int* __restrict__ ei, int* __restrict__ bucket_cnt, int E) {
    __shared__ int h[512];
    int t = threadIdx.x;
    for (int i = t; i < 512; i += 256) h[i] = 0;
    __syncthreads();
    int base = blockIdx.x * CHUNK;
    int lim = min(base + CHUNK, E);
    for (int e = base + t; e < lim; e += 256) {
        int d = ei[E + e];
        atomicAdd(&h[d >> 8], 1);
    }
    __syncthreads();
    for (int i = t; i < 512; i += 256)
        if (h[i]) atomicAdd(&bucket_cnt[i], h[i]);
}

__global__ void scan_buckets(const int* __restrict__ bucket_cnt,
                             int* __restrict__ bucket_base,
                             int* __restrict__ bucket_fill) {
    __shared__ int sh[512];
    int t = threadIdx.x;  // 512 threads
    int v = (t < NB) ? bucket_cnt[t] : 0;
    sh[t] = v;
    __syncthreads();
    for (int off = 1; off < 512; off <<= 1) {
        int u = (t >= off) ? sh[t - off] : 0;
        __syncthreads();
        sh[t] += u;
        __syncthreads();
    }
    int ex = (t == 0) ? 0 : sh[t - 1];
    if (t <= NB) bucket_base[t] = ex;
    if (t < NB) bucket_fill[t] = ex;
}

__global__ __launch_bounds__(256)
void coarse_scatter(const int* __restrict__ ei, int* __restrict__ bucket_fill,
                    unsigned long long* __restrict__ pairs, int E) {
    __shared__ int h[512];
    __shared__ int base[512];
    int t = threadIdx.x;
    for (int i = t; i < 512; i += 256) h[i] = 0;
    __syncthreads();
    int cbase = blockIdx.x * CHUNK;
    int lim = min(cbase + CHUNK, E);
    for (int e = cbase + t; e < lim; e += 256) {
        int d = ei[E + e];
        atomicAdd(&h[d >> 8], 1);
    }
    __syncthreads();
    for (int i = t; i < 512; i += 256)
        base[i] = h[i] ? atomicAdd(&bucket_fill[i], h[i]) : 0;
    __syncthreads();
    for (int i = t; i < 512; i += 256) h[i] = 0;
    __syncthreads();
    for (int e = cbase + t; e < lim; e += 256) {
        int s = ei[e];
        int d = ei[E + e];
        int b = d >> 8;
        int r = atomicAdd(&h[b], 1);
        pairs[base[b] + r] =
            ((unsigned long long)(unsigned)d << 32) | (unsigned)s;
    }
}

__global__ __launch_bounds__(256)
void fine_csr(const unsigned long long* __restrict__ pairs,
              const int* __restrict__ bucket_base,
              int* __restrict__ rowptr, int* __restrict__ colid,
              float* __restrict__ dinv, int n) {
    __shared__ int hist[256];
    __shared__ int offs[256];
    __shared__ int rank[256];
    __shared__ int lbuf[CAP];
    int b = blockIdx.x, t = threadIdx.x;
    int beg = bucket_base[b], end = bucket_base[b + 1];
    int cnt = end - beg;
    hist[t] = 0; rank[t] = 0;
    __syncthreads();
    for (int i = t; i < cnt; i += 256) {
        int d = (int)(pairs[beg + i] >> 32);
        atomicAdd(&hist[d & 255], 1);
    }
    __syncthreads();
    int v = hist[t];
    offs[t] = v;
    __syncthreads();
    for (int off = 1; off < 256; off <<= 1) {
        int u = (t >= off) ? offs[t - off] : 0;
        __syncthreads();
        offs[t] += u;
        __syncthreads();
    }
    int ex = (t == 0) ? 0 : offs[t - 1];
    int node = (b << 8) + t;
    if (node < n) {
        rowptr[node] = beg + ex;
        dinv[node] = rsqrtf((float)v + 1.0f);
    } else if (node == n) {
        rowptr[n] = beg + ex;
    }
    __syncthreads();
    offs[t] = ex;
    __syncthreads();
    for (int i = t; i < cnt; i += 256) {
        unsigned long long p = pairs[beg + i];
        int d = (int)(p >> 32) & 255;
        int s = (int)(p & 0xffffffffu);
        int r = atomicAdd(&rank[d], 1);
        lbuf[offs[d] + r] = s;
    }
    __syncthreads();
    for (int i = t; i < cnt; i += 256) colid[beg + i] = lbuf[i];
}

// ---------------- weight prep: W[K][OUT] fp32 -> swizzled bf16 hi/lo fragments ----
// all 6 layers in ONE launch (segment dispatch on flat index).

__device__ __forceinline__ void wsplit_one(const float* __restrict__ W,
                                           unsigned short* __restrict__ Wsw,
                                           int i, int K, int OUT) {
    int k = i / OUT, o = i % OUT;
    float w = W[i];
    unsigned u = __float_as_uint(w);
    float r = w - __uint_as_float(u & 0xFFFF0000u);
    int NT = OUT >> 4;
    int ktc = k >> 5, q = (k >> 3) & 3, j = k & 7;
    int nt = o >> 4, mm = o & 15;
    int lane = (q << 4) | mm;
    size_t base = ((((size_t)(ktc * NT + nt) * 2) * 64 + lane) << 3) + j;
    Wsw[base] = (unsigned short)(u >> 16);
    Wsw[base + 512] = (unsigned short)(__float_as_uint(r) >> 16);  // h=1: +64*8
}

__global__ __launch_bounds__(256)
void wsplit_all(const float* __restrict__ W0, unsigned short* __restrict__ O0,
                const float* __restrict__ W1, unsigned short* __restrict__ O1,
                const float* __restrict__ W2, unsigned short* __restrict__ O2,
                const float* __restrict__ W3, unsigned short* __restrict__ O3,
                const float* __restrict__ W4, unsigned short* __restrict__ O4,
                const float* __restrict__ W5, unsigned short* __restrict__ O5) {
    int i = blockIdx.x * 256 + threadIdx.x;
    // sizes: e1 20480, e2 16384, e3 8192, d1 12288, d2 16384, d3 16384
    if (i < 20480) { wsplit_one(W0, O0, i, 160, 128); return; }
    i -= 20480;
    if (i < 16384) { wsplit_one(W1, O1, i, 128, 128); return; }
    i -= 16384;
    if (i < 8192)  { wsplit_one(W2, O2, i, 128, 64);  return; }
    i -= 8192;
    if (i < 12288) { wsplit_one(W3, O3, i, 96, 128);  return; }
    i -= 12288;
    if (i < 16384) { wsplit_one(W4, O4, i, 128, 128); return; }
    i -= 16384;
    if (i < 16384) { wsplit_one(W5, O5, i, 128, 128); }
}

// ---------------- MFMA GEMM v2: 2 row-tiles per wave, B-frag register reuse ----
// Rationale: v1 was LDS-read-bound (16 ds_read_b128 ~192cyc vs 24 MFMA ~120cyc
// per wave-K-step). Each wave now owns TWO 16-row tiles; each B fragment pair
// (bhi,blo) is loaded once and feeds 6 MFMAs -> MFMA:ds_read = 3:1, MFMA
// becomes the critical path. 256 thr x 4 waves x 2 tiles = 8 tiles/block
// (same 782-block grid and LDS footprint as v1).
// Y16 row-major fp16: Y[row*OUT + o] = (X@W)[row][o] * dinv[row].
// Two input pointers: columns [0,K1) from X1 (stride K1), [K1,K) from X2.

__device__ __forceinline__ void split8(const float* v, shortx8& hi, shortx8& lo) {
#pragma unroll
    for (int i = 0; i < 8; i++) {
        unsigned u = __float_as_uint(v[i]);
        float r = v[i] - __uint_as_float(u & 0xFFFF0000u);
        hi[i] = (short)(u >> 16);
        lo[i] = (short)(__float_as_uint(r) >> 16);
    }
}

template <int OUT, int K, int K1>
__global__ __launch_bounds__(256)
void gemm_mfma(const float* __restrict__ X1, const float* __restrict__ X2,
               const unsigned short* __restrict__ Wsw,
               const float* __restrict__ dinv,
               __half* __restrict__ Y, int ntiles) {
    constexpr int NT = OUT / 16;
    constexpr int NKTC = K / 32;
    constexpr int K2 = K - K1;
    constexpr int PERC = OUT * 128;  // bytes per ktc chunk
    constexpr int CSZ = (65536 / PERC < NKTC) ? (65536 / PERC) : NKTC;
    __shared__ __align__(16) unsigned short lds[CSZ * PERC / 2];

    const int t = threadIdx.x;
    const int wave = t >> 6, lane = t & 63;
    const int m = lane & 15, q = lane >> 4;
    const int tile0 = blockIdx.x * 8 + wave * 2;
    const int tile1 = tile0 + 1;
    const bool act0 = tile0 < ntiles;
    const bool act1 = tile1 < ntiles;
    const int r0 = act0 ? tile0 * 16 + m : 0;
    const int r1 = act1 ? tile1 * 16 + m : 0;
    const float* ap1a = X1 + (size_t)r0 * K1 + q * 8;
    const float* ap1b = X1 + (size_t)r1 * K1 + q * 8;
    const float* ap2a = (K2 > 0) ? (X2 + (size_t)r0 * K2 + q * 8) : X1;
    const float* ap2b = (K2 > 0) ? (X2 + (size_t)r1 * K2 + q * 8) : X1;

    floatx4 acc0[NT], acc1[NT];
#pragma unroll
    for (int nt = 0; nt < NT; nt++) {
        acc0[nt] = (floatx4){0.f, 0.f, 0.f, 0.f};
        acc1[nt] = (floatx4){0.f, 0.f, 0.f, 0.f};
    }

#pragma unroll
    for (int c0 = 0; c0 < NKTC; c0 += CSZ) {
        const int cl = (NKTC - c0 < CSZ) ? (NKTC - c0) : CSZ;
        if (c0 != 0) __syncthreads();
        {
            const float4* gs = (const float4*)Wsw + (size_t)c0 * (PERC / 16);
            float4* ld = (float4*)lds;
            int tot = cl * (PERC / 16);
            for (int i = t; i < tot; i += 256) ld[i] = gs[i];
        }
        __syncthreads();
#pragma unroll
        for (int ktc = 0; ktc < cl; ktc++) {
            const int kg = (c0 + ktc) * 32;
            const float* pa = (kg < K1) ? (ap1a + kg) : (ap2a + (kg - K1));
            const float* pb = (kg < K1) ? (ap1b + kg) : (ap2b + (kg - K1));
            float av0[8], av1[8];
            *(float4*)&av0[0] = *(const float4*)(pa);
            *(float4*)&av0[4] = *(const float4*)(pa + 4);
            *(float4*)&av1[0] = *(const float4*)(pb);
            *(float4*)&av1[4] = *(const float4*)(pb + 4);
            shortx8 ahi0, alo0, ahi1, alo1;
            split8(av0, ahi0, alo0);
            split8(av1, ahi1, alo1);
#pragma unroll
            for (int nt = 0; nt < NT; nt++) {
                const unsigned short* fb =
                    lds + ((((ktc * NT + nt) * 2) * 64 + lane) << 3);
                shortx8 bhi = *(const shortx8*)fb;
                shortx8 blo = *(const shortx8*)(fb + 512);
                acc0[nt] = __builtin_amdgcn_mfma_f32_16x16x32_bf16(ahi0, bhi, acc0[nt], 0, 0, 0);
                acc0[nt] = __builtin_amdgcn_mfma_f32_16x16x32_bf16(ahi0, blo, acc0[nt], 0, 0, 0);
                acc0[nt] = __builtin_amdgcn_mfma_f32_16x16x32_bf16(alo0, bhi, acc0[nt], 0, 0, 0);
                acc1[nt] = __builtin_amdgcn_mfma_f32_16x16x32_bf16(ahi1, bhi, acc1[nt], 0, 0, 0);
                acc1[nt] = __builtin_amdgcn_mfma_f32_16x16x32_bf16(ahi1, blo, acc1[nt], 0, 0, 0);
                acc1[nt] = __builtin_amdgcn_mfma_f32_16x16x32_bf16(alo1, bhi, acc1[nt], 0, 0, 0);
            }
        }
    }

    if (act0) {
        float di[4];
#pragma unroll
        for (int r = 0; r < 4; r++) di[r] = dinv[tile0 * 16 + q * 4 + r];
#pragma unroll
        for (int nt = 0; nt < NT; nt++) {
#pragma unroll
            for (int r = 0; r < 4; r++) {
                int orow = tile0 * 16 + q * 4 + r;
                Y[(size_t)orow * OUT + nt * 16 + m] =
                    __float2half_rn(acc0[nt][r] * di[r]);
            }
        }
    }
    if (act1) {
        float di[4];
#pragma unroll
        for (int r = 0; r < 4; r++) di[r] = dinv[tile1 * 16 + q * 4 + r];
#pragma unroll
        for (int nt = 0; nt < NT; nt++) {
#pragma unroll
            for (int r = 0; r < 4; r++) {
                int orow = tile1 * 16 + q * 4 + r;
                Y[(size_t)orow * OUT + nt * 16 + m] =
                    __float2half_rn(acc1[nt][r] * di[r]);
            }
        }
    }
}

// ---------------- propagation: row-major gather, G edges per instruction ----------------
// PROVEN config (round 3: 70.8 us, 192 MB fetch — empirical request-rate
// roofline; chunked variants measured worse 3x, see rounds 1/4/5).
// Wave = 1 node. Lane loads 8 B; LPR = OUT/4 lanes cover one row, G = 64/LPR
// edges per gather instruction. Cross-group shfl_xor reduce; group 0 finalizes.

template <int OUT, bool TANH>
__global__ __launch_bounds__(256)
void prop_row(const __half2* __restrict__ hs, const float* __restrict__ dinv,
              const int* __restrict__ rowptr, const int* __restrict__ colid,
              const float* __restrict__ bias, float* __restrict__ out,
              int ldo, int n) {
    constexpr int LPR = OUT / 4;   // lanes per row (8 B per lane)
    constexpr int G = 64 / LPR;    // edges per gather instruction
    constexpr int RS2 = OUT / 4;   // float2 (2x half2) per row

    int wave = threadIdx.x >> 6, lane = threadIdx.x & 63;
    int node = blockIdx.x * 4 + wave;
    if (node >= n) return;
    int g = lane / LPR, fq = lane % LPR;
    int beg = rowptr[node], end = rowptr[node + 1];
    const float2* __restrict__ b2 = (const float2*)hs;

    float ax = 0.f, ay = 0.f, az = 0.f, aw = 0.f;
    int e = beg;
    for (; e + 8 * G <= end; e += 8 * G) {
        int s[8];
#pragma unroll
        for (int j = 0; j < 8; j++) s[j] = colid[e + j * G + g];
        float2 v[8];
#pragma unroll
        for (int j = 0; j < 8; j++) v[j] = b2[(size_t)s[j] * RS2 + fq];
#pragma unroll
        for (int j = 0; j < 8; j++) {
            float2 f0 = __half22float2(*(const __half2*)&v[j].x);
            float2 f1 = __half22float2(*(const __half2*)&v[j].y);
            ax += f0.x; ay += f0.y; az += f1.x; aw += f1.y;
        }
    }
    if (e + 4 * G <= end) {
        int s[4];
#pragma unroll
        for (int j = 0; j < 4; j++) s[j] = colid[e + j * G + g];
        float2 v[4];
#pragma unroll
        for (int j = 0; j < 4; j++) v[j] = b2[(size_t)s[j] * RS2 + fq];
#pragma unroll
        for (int j = 0; j < 4; j++) {
            float2 f0 = __half22float2(*(const __half2*)&v[j].x);
            float2 f1 = __half22float2(*(const __half2*)&v[j].y);
            ax += f0.x; ay += f0.y; az += f1.x; aw += f1.y;
        }
        e += 4 * G;
    }
    for (; e + G <= end; e += G) {
        int s = colid[e + g];
        float2 v = b2[(size_t)s * RS2 + fq];
        float2 f0 = __half22float2(*(const __half2*)&v.x);
        float2 f1 = __half22float2(*(const __half2*)&v.y);
        ax += f0.x; ay += f0.y; az += f1.x; aw += f1.y;
    }
    if (e + g < end) {
        int s = colid[e + g];
        float2 v = b2[(size_t)s * RS2 + fq];
        float2 f0 = __half22float2(*(const __half2*)&v.x);
        float2 f1 = __half22float2(*(const __half2*)&v.y);
        ax += f0.x; ay += f0.y; az += f1.x; aw += f1.y;
    }

    // reduce across the G edge-groups (lanes differing in group bits)
    if constexpr (G >= 2) {
        ax += __shfl_xor(ax, LPR); ay += __shfl_xor(ay, LPR);
        az += __shfl_xor(az, LPR); aw += __shfl_xor(aw, LPR);
    }
    if constexpr (G == 4) {
        ax += __shfl_xor(ax, 2 * LPR); ay += __shfl_xor(ay, 2 * LPR);
        az += __shfl_xor(az, 2 * LPR); aw += __shfl_xor(aw, 2 * LPR);
    }

    if (g == 0) {
        float2 sv = b2[(size_t)node * RS2 + fq];
        float2 f0 = __half22float2(*(const __half2*)&sv.x);
        float2 f1 = __half22float2(*(const __half2*)&sv.y);
        ax += f0.x; ay += f0.y; az += f1.x; aw += f1.y;
        float di = dinv[node];
        float4 bb = *(const float4*)(bias + fq * 4);
        float ox = di * ax + bb.x;
        float oy = di * ay + bb.y;
        float oz = di * az + bb.z;
        float ow = di * aw + bb.w;
        if (TANH) { ox = tanhf(ox); oy = tanhf(oy); oz = tanhf(oz); ow = tanhf(ow); }
        *(float4*)(out + (size_t)node * ldo + fq * 4) = make_float4(ox, oy, oz, ow);
    }
}

// ---------------- launch ----------------

extern "C" void kernel_launch(void* const* d_in, const int* in_sizes, int n_in,
                              void* d_out, int out_size, void* d_ws, size_t ws_size,
                              hipStream_t stream) {
    const int n = NN, E = NE;
    const float* feature   = (const float*)d_in[0];
    const float* condition = (const float*)d_in[1];
    const int*   ei        = (const int*)d_in[2];
    const float* W_e1 = (const float*)d_in[3];  const float* b_e1 = (const float*)d_in[4];
    const float* W_e2 = (const float*)d_in[5];  const float* b_e2 = (const float*)d_in[6];
    const float* W_e3 = (const float*)d_in[7];  const float* b_e3 = (const float*)d_in[8];
    const float* W_d1 = (const float*)d_in[9];  const float* b_d1 = (const float*)d_in[10];
    const float* W_d2 = (const float*)d_in[11]; const float* b_d2 = (const float*)d_in[12];
    const float* W_d3 = (const float*)d_in[13]; const float* b_d3 = (const float*)d_in[14];
    float* out = (float*)d_out;

    float*  A    = (float*)d_ws;                    // n*160 floats
    __half* H16  = (__half*)(A + (size_t)n * 160);  // n*128 halves
    float*  dinv = (float*)(H16 + (size_t)n * 128); // n
    int* rowptr  = (int*)(dinv + n);                // n+1
    int* colid   = rowptr + n + 1;                  // E
    uintptr_t pp = (uintptr_t)(colid + E);
    pp = (pp + 15) & ~(uintptr_t)15;
    unsigned long long* pairs = (unsigned long long*)pp;  // E
    int* bucket_cnt  = (int*)(pairs + E);           // 512
    int* bucket_base = bucket_cnt + 512;            // 512
    int* bucket_fill = bucket_base + 512;           // 512
    uintptr_t wp = (uintptr_t)(bucket_fill + 512);
    wp = (wp + 15) & ~(uintptr_t)15;
    unsigned short* wt = (unsigned short*)wp;
    unsigned short* e1w = wt;              unsigned short* e2w = e1w + 160 * 128 * 2;
    unsigned short* e3w = e2w + 128*128*2; unsigned short* d1w = e3w + 128 * 64 * 2;
    unsigned short* d2w = d1w + 96*128*2;  unsigned short* d3w = d2w + 128 * 128 * 2;

    hipMemsetAsync(bucket_cnt, 0, 512 * sizeof(int), stream);

    int nbc = (E + CHUNK - 1) / CHUNK;
    coarse_hist<<<nbc, 256, 0, stream>>>(ei, bucket_cnt, E);
    scan_buckets<<<1, 512, 0, stream>>>(bucket_cnt, bucket_base, bucket_fill);
    coarse_scatter<<<nbc, 256, 0, stream>>>(ei, bucket_fill, pairs, E);
    fine_csr<<<NB, 256, 0, stream>>>(pairs, bucket_base, rowptr, colid, dinv, n);

    wsplit_all<<<(90112 + 255) / 256, 256, 0, stream>>>(
        W_e1, e1w, W_e2, e2w, W_e3, e3w, W_d1, d1w, W_d2, d2w, W_d3, d3w);

    const int ntiles = n / 16;          // 6250 exactly
    const int gb = (ntiles + 7) / 8;    // 782 blocks: 4 waves x 2 tiles each
    const int pb = (n + 3) / 4;         // 25000 blocks, 1 wave per node

    // encoder (e1 reads feature+condition directly; no concat)
    gemm_mfma<128, 160, 128><<<gb, 256, 0, stream>>>(feature, condition, e1w, dinv, H16, ntiles);
    prop_row<128, true><<<pb, 256, 0, stream>>>((const __half2*)H16, dinv, rowptr, colid, b_e1, A, 128, n);
    gemm_mfma<128, 128, 128><<<gb, 256, 0, stream>>>(A, nullptr, e2w, dinv, H16, ntiles);
    prop_row<128, true><<<pb, 256, 0, stream>>>((const __half2*)H16, dinv, rowptr, colid, b_e2, A, 128, n);
    gemm_mfma<64, 128, 128><<<gb, 256, 0, stream>>>(A, nullptr, e3w, dinv, H16, ntiles);
    prop_row<64, false><<<pb, 256, 0, stream>>>((const __half2*)H16, dinv, rowptr, colid, b_e3, A, 64, n);

    // decoder (d1 reads z (ld=64) + condition directly; no condcopy)
    gemm_mfma<128, 96, 64><<<gb, 256, 0, stream>>>(A, condition, d1w, dinv, H16, ntiles);
    prop_row<128, true><<<pb, 256, 0, stream>>>((const __half2*)H16, dinv, rowptr, colid, b_d1, A, 128, n);
    gemm_mfma<128, 128, 128><<<gb, 256, 0, stream>>>(A, nullptr, d2w, dinv, H16, ntiles);
    prop_row<128, true><<<pb, 256, 0, stream>>>((const __half2*)H16, dinv, rowptr, colid, b_d2, A, 128, n);
    gemm_mfma<128, 128, 128><<<gb, 256, 0, stream>>>(A, nullptr, d3w, dinv, H16, ntiles);
    prop_row<128, false><<<pb, 256, 0, stream>>>((const __half2*)H16, dinv, rowptr, colid, b_d3, out, 128, n);
}

// Round 7
// 691.231 us; speedup vs baseline: 1.7235x; 1.0491x over previous
//
#include <hip/hip_runtime.h>
#include <hip/hip_fp16.h>
#include <math.h>

#define NN 100000
#define NE 1600000
#define NB ((NN + 255) >> 8)   // 391 buckets of 256 nodes
#define CHUNK 8192
#define CAP 8192

typedef __attribute__((ext_vector_type(4))) float floatx4;
typedef __attribute__((ext_vector_type(8))) short shortx8;

// ---------------- bucketed CSR build ----------------

__global__ __launch_bounds__(256)
void coarse_hist(const int* __restrict__ ei, int* __restrict__ bucket_cnt, int E) {
    __shared__ int h[512];
    int t = threadIdx.x;
    for (int i = t; i < 512; i += 256) h[i] = 0;
    __syncthreads();
    int base = blockIdx.x * CHUNK;
    int lim = min(base + CHUNK, E);
    for (int e = base + t; e < lim; e += 256) {
        int d = ei[E + e];
        atomicAdd(&h[d >> 8], 1);
    }
    __syncthreads();
    for (int i = t; i < 512; i += 256)
        if (h[i]) atomicAdd(&bucket_cnt[i], h[i]);
}

__global__ void scan_buckets(const int* __restrict__ bucket_cnt,
                             int* __restrict__ bucket_base,
                             int* __restrict__ bucket_fill) {
    __shared__ int sh[512];
    int t = threadIdx.x;  // 512 threads
    int v = (t < NB) ? bucket_cnt[t] : 0;
    sh[t] = v;
    __syncthreads();
    for (int off = 1; off < 512; off <<= 1) {
        int u = (t >= off) ? sh[t - off] : 0;
        __syncthreads();
        sh[t] += u;
        __syncthreads();
    }
    int ex = (t == 0) ? 0 : sh[t - 1];
    if (t <= NB) bucket_base[t] = ex;
    if (t < NB) bucket_fill[t] = ex;
}

__global__ __launch_bounds__(256)
void coarse_scatter(const int* __restrict__ ei, int* __restrict__ bucket_fill,
                    unsigned long long* __restrict__ pairs, int E) {
    __shared__ int h[512];
    __shared__ int base[512];
    int t = threadIdx.x;
    for (int i = t; i < 512; i += 256) h[i] = 0;
    __syncthreads();
    int cbase = blockIdx.x * CHUNK;
    int lim = min(cbase + CHUNK, E);
    for (int e = cbase + t; e < lim; e += 256) {
        int d = ei[E + e];
        atomicAdd(&h[d >> 8], 1);
    }
    __syncthreads();
    for (int i = t; i < 512; i += 256)
        base[i] = h[i] ? atomicAdd(&bucket_fill[i], h[i]) : 0;
    __syncthreads();
    for (int i = t; i < 512; i += 256) h[i] = 0;
    __syncthreads();
    for (int e = cbase + t; e < lim; e += 256) {
        int s = ei[e];
        int d = ei[E + e];
        int b = d >> 8;
        int r = atomicAdd(&h[b], 1);
        pairs[base[b] + r] =
            ((unsigned long long)(unsigned)d << 32) | (unsigned)s;
    }
}

__global__ __launch_bounds__(256)
void fine_csr(const unsigned long long* __restrict__ pairs,
              const int* __restrict__ bucket_base,
              int* __restrict__ rowptr, int* __restrict__ colid,
              float* __restrict__ dinv, int n) {
    __shared__ int hist[256];
    __shared__ int offs[256];
    __shared__ int rank[256];
    __shared__ int lbuf[CAP];
    int b = blockIdx.x, t = threadIdx.x;
    int beg = bucket_base[b], end = bucket_base[b + 1];
    int cnt = end - beg;
    hist[t] = 0; rank[t] = 0;
    __syncthreads();
    for (int i = t; i < cnt; i += 256) {
        int d = (int)(pairs[beg + i] >> 32);
        atomicAdd(&hist[d & 255], 1);
    }
    __syncthreads();
    int v = hist[t];
    offs[t] = v;
    __syncthreads();
    for (int off = 1; off < 256; off <<= 1) {
        int u = (t >= off) ? offs[t - off] : 0;
        __syncthreads();
        offs[t] += u;
        __syncthreads();
    }
    int ex = (t == 0) ? 0 : offs[t - 1];
    int node = (b << 8) + t;
    if (node < n) {
        rowptr[node] = beg + ex;
        dinv[node] = rsqrtf((float)v + 1.0f);
    } else if (node == n) {
        rowptr[n] = beg + ex;
    }
    __syncthreads();
    offs[t] = ex;
    __syncthreads();
    for (int i = t; i < cnt; i += 256) {
        unsigned long long p = pairs[beg + i];
        int d = (int)(p >> 32) & 255;
        int s = (int)(p & 0xffffffffu);
        int r = atomicAdd(&rank[d], 1);
        lbuf[offs[d] + r] = s;
    }
    __syncthreads();
    for (int i = t; i < cnt; i += 256) colid[beg + i] = lbuf[i];
}

// ---------------- weight prep: W[K][OUT] fp32 -> swizzled bf16 hi/lo fragments ----
// all 6 layers in ONE launch (segment dispatch on flat index).

__device__ __forceinline__ void wsplit_one(const float* __restrict__ W,
                                           unsigned short* __restrict__ Wsw,
                                           int i, int K, int OUT) {
    int k = i / OUT, o = i % OUT;
    float w = W[i];
    unsigned u = __float_as_uint(w);
    float r = w - __uint_as_float(u & 0xFFFF0000u);
    int NT = OUT >> 4;
    int ktc = k >> 5, q = (k >> 3) & 3, j = k & 7;
    int nt = o >> 4, mm = o & 15;
    int lane = (q << 4) | mm;
    size_t base = ((((size_t)(ktc * NT + nt) * 2) * 64 + lane) << 3) + j;
    Wsw[base] = (unsigned short)(u >> 16);
    Wsw[base + 512] = (unsigned short)(__float_as_uint(r) >> 16);  // h=1: +64*8
}

__global__ __launch_bounds__(256)
void wsplit_all(const float* __restrict__ W0, unsigned short* __restrict__ O0,
                const float* __restrict__ W1, unsigned short* __restrict__ O1,
                const float* __restrict__ W2, unsigned short* __restrict__ O2,
                const float* __restrict__ W3, unsigned short* __restrict__ O3,
                const float* __restrict__ W4, unsigned short* __restrict__ O4,
                const float* __restrict__ W5, unsigned short* __restrict__ O5) {
    int i = blockIdx.x * 256 + threadIdx.x;
    // sizes: e1 20480, e2 16384, e3 8192, d1 12288, d2 16384, d3 16384
    if (i < 20480) { wsplit_one(W0, O0, i, 160, 128); return; }
    i -= 20480;
    if (i < 16384) { wsplit_one(W1, O1, i, 128, 128); return; }
    i -= 16384;
    if (i < 8192)  { wsplit_one(W2, O2, i, 128, 64);  return; }
    i -= 8192;
    if (i < 12288) { wsplit_one(W3, O3, i, 96, 128);  return; }
    i -= 12288;
    if (i < 16384) { wsplit_one(W4, O4, i, 128, 128); return; }
    i -= 16384;
    if (i < 16384) { wsplit_one(W5, O5, i, 128, 128); }
}

// ---------------- MFMA GEMM v3: 512 thr, 8 waves x 2 row-tiles ----------------
// Round-6 lesson: 2-tile B-reuse at 256 thr halved occupancy (8 waves/CU) and
// regressed. v3 keeps round-3's 512-thr/64KB shape (2 blocks/CU = 16 waves/CU,
// enforced via __launch_bounds__(512,4) -> VGPR <= 128) while each wave owns
// TWO 16-row tiles: 16 ds_read_b128 per K-step now feed 48 MFMAs (was 24),
// and each B fragment pair drives two independent acc chains (2x MFMA ILP).
// Y16 row-major fp16: Y[row*OUT + o] = (X@W)[row][o] * dinv[row].
// Two input pointers: columns [0,K1) from X1 (stride K1), [K1,K) from X2.

__device__ __forceinline__ void split8(const float* v, shortx8& hi, shortx8& lo) {
#pragma unroll
    for (int i = 0; i < 8; i++) {
        unsigned u = __float_as_uint(v[i]);
        float r = v[i] - __uint_as_float(u & 0xFFFF0000u);
        hi[i] = (short)(u >> 16);
        lo[i] = (short)(__float_as_uint(r) >> 16);
    }
}

template <int OUT, int K, int K1>
__global__ __launch_bounds__(512, 4)
void gemm_mfma(const float* __restrict__ X1, const float* __restrict__ X2,
               const unsigned short* __restrict__ Wsw,
               const float* __restrict__ dinv,
               __half* __restrict__ Y, int ntiles) {
    constexpr int NT = OUT / 16;
    constexpr int NKTC = K / 32;
    constexpr int K2 = K - K1;
    constexpr int PERC = OUT * 128;  // bytes per ktc chunk
    constexpr int CSZ = (65536 / PERC < NKTC) ? (65536 / PERC) : NKTC;
    __shared__ __align__(16) unsigned short lds[CSZ * PERC / 2];

    const int t = threadIdx.x;
    const int wave = t >> 6, lane = t & 63;
    const int m = lane & 15, q = lane >> 4;
    const int tile0 = blockIdx.x * 16 + wave * 2;
    const int tile1 = tile0 + 1;
    const bool act0 = tile0 < ntiles;
    const bool act1 = tile1 < ntiles;
    const int r0 = act0 ? tile0 * 16 + m : 0;
    const int r1 = act1 ? tile1 * 16 + m : 0;
    const float* ap1a = X1 + (size_t)r0 * K1 + q * 8;
    const float* ap1b = X1 + (size_t)r1 * K1 + q * 8;
    const float* ap2a = (K2 > 0) ? (X2 + (size_t)r0 * K2 + q * 8) : X1;
    const float* ap2b = (K2 > 0) ? (X2 + (size_t)r1 * K2 + q * 8) : X1;

    floatx4 acc0[NT], acc1[NT];
#pragma unroll
    for (int nt = 0; nt < NT; nt++) {
        acc0[nt] = (floatx4){0.f, 0.f, 0.f, 0.f};
        acc1[nt] = (floatx4){0.f, 0.f, 0.f, 0.f};
    }

#pragma unroll
    for (int c0 = 0; c0 < NKTC; c0 += CSZ) {
        const int cl = (NKTC - c0 < CSZ) ? (NKTC - c0) : CSZ;
        if (c0 != 0) __syncthreads();
        {
            const float4* gs = (const float4*)Wsw + (size_t)c0 * (PERC / 16);
            float4* ld = (float4*)lds;
            int tot = cl * (PERC / 16);
            for (int i = t; i < tot; i += 512) ld[i] = gs[i];
        }
        __syncthreads();
#pragma unroll
        for (int ktc = 0; ktc < cl; ktc++) {
            const int kg = (c0 + ktc) * 32;
            const float* pa = (kg < K1) ? (ap1a + kg) : (ap2a + (kg - K1));
            const float* pb = (kg < K1) ? (ap1b + kg) : (ap2b + (kg - K1));
            float av0[8], av1[8];
            *(float4*)&av0[0] = *(const float4*)(pa);
            *(float4*)&av0[4] = *(const float4*)(pa + 4);
            *(float4*)&av1[0] = *(const float4*)(pb);
            *(float4*)&av1[4] = *(const float4*)(pb + 4);
            shortx8 ahi0, alo0, ahi1, alo1;
            split8(av0, ahi0, alo0);
            split8(av1, ahi1, alo1);
#pragma unroll
            for (int nt = 0; nt < NT; nt++) {
                const unsigned short* fb =
                    lds + ((((ktc * NT + nt) * 2) * 64 + lane) << 3);
                shortx8 bhi = *(const shortx8*)fb;
                shortx8 blo = *(const shortx8*)(fb + 512);
                acc0[nt] = __builtin_amdgcn_mfma_f32_16x16x32_bf16(ahi0, bhi, acc0[nt], 0, 0, 0);
                acc1[nt] = __builtin_amdgcn_mfma_f32_16x16x32_bf16(ahi1, bhi, acc1[nt], 0, 0, 0);
                acc0[nt] = __builtin_amdgcn_mfma_f32_16x16x32_bf16(ahi0, blo, acc0[nt], 0, 0, 0);
                acc1[nt] = __builtin_amdgcn_mfma_f32_16x16x32_bf16(ahi1, blo, acc1[nt], 0, 0, 0);
                acc0[nt] = __builtin_amdgcn_mfma_f32_16x16x32_bf16(alo0, bhi, acc0[nt], 0, 0, 0);
                acc1[nt] = __builtin_amdgcn_mfma_f32_16x16x32_bf16(alo1, bhi, acc1[nt], 0, 0, 0);
            }
        }
    }

    if (act0) {
        float di[4];
#pragma unroll
        for (int r = 0; r < 4; r++) di[r] = dinv[tile0 * 16 + q * 4 + r];
#pragma unroll
        for (int nt = 0; nt < NT; nt++) {
#pragma unroll
            for (int r = 0; r < 4; r++) {
                int orow = tile0 * 16 + q * 4 + r;
                Y[(size_t)orow * OUT + nt * 16 + m] =
                    __float2half_rn(acc0[nt][r] * di[r]);
            }
        }
    }
    if (act1) {
        float di[4];
#pragma unroll
        for (int r = 0; r < 4; r++) di[r] = dinv[tile1 * 16 + q * 4 + r];
#pragma unroll
        for (int nt = 0; nt < NT; nt++) {
#pragma unroll
            for (int r = 0; r < 4; r++) {
                int orow = tile1 * 16 + q * 4 + r;
                Y[(size_t)orow * OUT + nt * 16 + m] =
                    __float2half_rn(acc1[nt][r] * di[r]);
            }
        }
    }
}

// ---------------- propagation: row-major gather, G edges per instruction ----------------
// PROVEN config (rounds 3/6: 70.5-71 us, 192 MB fetch = compulsory L2-miss
// floor; within ~20% of the ~115 G-segments/s scatter ceiling measured across
// two kernel families in rounds 0-5 — do not touch).

template <int OUT, bool TANH>
__global__ __launch_bounds__(256)
void prop_row(const __half2* __restrict__ hs, const float* __restrict__ dinv,
              const int* __restrict__ rowptr, const int* __restrict__ colid,
              const float* __restrict__ bias, float* __restrict__ out,
              int ldo, int n) {
    constexpr int LPR = OUT / 4;   // lanes per row (8 B per lane)
    constexpr int G = 64 / LPR;    // edges per gather instruction
    constexpr int RS2 = OUT / 4;   // float2 (2x half2) per row

    int wave = threadIdx.x >> 6, lane = threadIdx.x & 63;
    int node = blockIdx.x * 4 + wave;
    if (node >= n) return;
    int g = lane / LPR, fq = lane % LPR;
    int beg = rowptr[node], end = rowptr[node + 1];
    const float2* __restrict__ b2 = (const float2*)hs;

    float ax = 0.f, ay = 0.f, az = 0.f, aw = 0.f;
    int e = beg;
    for (; e + 8 * G <= end; e += 8 * G) {
        int s[8];
#pragma unroll
        for (int j = 0; j < 8; j++) s[j] = colid[e + j * G + g];
        float2 v[8];
#pragma unroll
        for (int j = 0; j < 8; j++) v[j] = b2[(size_t)s[j] * RS2 + fq];
#pragma unroll
        for (int j = 0; j < 8; j++) {
            float2 f0 = __half22float2(*(const __half2*)&v[j].x);
            float2 f1 = __half22float2(*(const __half2*)&v[j].y);
            ax += f0.x; ay += f0.y; az += f1.x; aw += f1.y;
        }
    }
    if (e + 4 * G <= end) {
        int s[4];
#pragma unroll
        for (int j = 0; j < 4; j++) s[j] = colid[e + j * G + g];
        float2 v[4];
#pragma unroll
        for (int j = 0; j < 4; j++) v[j] = b2[(size_t)s[j] * RS2 + fq];
#pragma unroll
        for (int j = 0; j < 4; j++) {
            float2 f0 = __half22float2(*(const __half2*)&v[j].x);
            float2 f1 = __half22float2(*(const __half2*)&v[j].y);
            ax += f0.x; ay += f0.y; az += f1.x; aw += f1.y;
        }
        e += 4 * G;
    }
    for (; e + G <= end; e += G) {
        int s = colid[e + g];
        float2 v = b2[(size_t)s * RS2 + fq];
        float2 f0 = __half22float2(*(const __half2*)&v.x);
        float2 f1 = __half22float2(*(const __half2*)&v.y);
        ax += f0.x; ay += f0.y; az += f1.x; aw += f1.y;
    }
    if (e + g < end) {
        int s = colid[e + g];
        float2 v = b2[(size_t)s * RS2 + fq];
        float2 f0 = __half22float2(*(const __half2*)&v.x);
        float2 f1 = __half22float2(*(const __half2*)&v.y);
        ax += f0.x; ay += f0.y; az += f1.x; aw += f1.y;
    }

    // reduce across the G edge-groups (lanes differing in group bits)
    if constexpr (G >= 2) {
        ax += __shfl_xor(ax, LPR); ay += __shfl_xor(ay, LPR);
        az += __shfl_xor(az, LPR); aw += __shfl_xor(aw, LPR);
    }
    if constexpr (G == 4) {
        ax += __shfl_xor(ax, 2 * LPR); ay += __shfl_xor(ay, 2 * LPR);
        az += __shfl_xor(az, 2 * LPR); aw += __shfl_xor(aw, 2 * LPR);
    }

    if (g == 0) {
        float2 sv = b2[(size_t)node * RS2 + fq];
        float2 f0 = __half22float2(*(const __half2*)&sv.x);
        float2 f1 = __half22float2(*(const __half2*)&sv.y);
        ax += f0.x; ay += f0.y; az += f1.x; aw += f1.y;
        float di = dinv[node];
        float4 bb = *(const float4*)(bias + fq * 4);
        float ox = di * ax + bb.x;
        float oy = di * ay + bb.y;
        float oz = di * az + bb.z;
        float ow = di * aw + bb.w;
        if (TANH) { ox = tanhf(ox); oy = tanhf(oy); oz = tanhf(oz); ow = tanhf(ow); }
        *(float4*)(out + (size_t)node * ldo + fq * 4) = make_float4(ox, oy, oz, ow);
    }
}

// ---------------- launch ----------------

extern "C" void kernel_launch(void* const* d_in, const int* in_sizes, int n_in,
                              void* d_out, int out_size, void* d_ws, size_t ws_size,
                              hipStream_t stream) {
    const int n = NN, E = NE;
    const float* feature   = (const float*)d_in[0];
    const float* condition = (const float*)d_in[1];
    const int*   ei        = (const int*)d_in[2];
    const float* W_e1 = (const float*)d_in[3];  const float* b_e1 = (const float*)d_in[4];
    const float* W_e2 = (const float*)d_in[5];  const float* b_e2 = (const float*)d_in[6];
    const float* W_e3 = (const float*)d_in[7];  const float* b_e3 = (const float*)d_in[8];
    const float* W_d1 = (const float*)d_in[9];  const float* b_d1 = (const float*)d_in[10];
    const float* W_d2 = (const float*)d_in[11]; const float* b_d2 = (const float*)d_in[12];
    const float* W_d3 = (const float*)d_in[13]; const float* b_d3 = (const float*)d_in[14];
    float* out = (float*)d_out;

    float*  A    = (float*)d_ws;                    // n*160 floats
    __half* H16  = (__half*)(A + (size_t)n * 160);  // n*128 halves
    float*  dinv = (float*)(H16 + (size_t)n * 128); // n
    int* rowptr  = (int*)(dinv + n);                // n+1
    int* colid   = rowptr + n + 1;                  // E
    uintptr_t pp = (uintptr_t)(colid + E);
    pp = (pp + 15) & ~(uintptr_t)15;
    unsigned long long* pairs = (unsigned long long*)pp;  // E
    int* bucket_cnt  = (int*)(pairs + E);           // 512
    int* bucket_base = bucket_cnt + 512;            // 512
    int* bucket_fill = bucket_base + 512;           // 512
    uintptr_t wp = (uintptr_t)(bucket_fill + 512);
    wp = (wp + 15) & ~(uintptr_t)15;
    unsigned short* wt = (unsigned short*)wp;
    unsigned short* e1w = wt;              unsigned short* e2w = e1w + 160 * 128 * 2;
    unsigned short* e3w = e2w + 128*128*2; unsigned short* d1w = e3w + 128 * 64 * 2;
    unsigned short* d2w = d1w + 96*128*2;  unsigned short* d3w = d2w + 128 * 128 * 2;

    hipMemsetAsync(bucket_cnt, 0, 512 * sizeof(int), stream);

    int nbc = (E + CHUNK - 1) / CHUNK;
    coarse_hist<<<nbc, 256, 0, stream>>>(ei, bucket_cnt, E);
    scan_buckets<<<1, 512, 0, stream>>>(bucket_cnt, bucket_base, bucket_fill);
    coarse_scatter<<<nbc, 256, 0, stream>>>(ei, bucket_fill, pairs, E);
    fine_csr<<<NB, 256, 0, stream>>>(pairs, bucket_base, rowptr, colid, dinv, n);

    wsplit_all<<<(90112 + 255) / 256, 256, 0, stream>>>(
        W_e1, e1w, W_e2, e2w, W_e3, e3w, W_d1, d1w, W_d2, d2w, W_d3, d3w);

    const int ntiles = n / 16;          // 6250 exactly
    const int gb = (ntiles + 15) / 16;  // 391 blocks: 8 waves x 2 tiles each
    const int pb = (n + 3) / 4;         // 25000 blocks, 1 wave per node

    // encoder (e1 reads feature+condition directly; no concat)
    gemm_mfma<128, 160, 128><<<gb, 512, 0, stream>>>(feature, condition, e1w, dinv, H16, ntiles);
    prop_row<128, true><<<pb, 256, 0, stream>>>((const __half2*)H16, dinv, rowptr, colid, b_e1, A, 128, n);
    gemm_mfma<128, 128, 128><<<gb, 512, 0, stream>>>(A, nullptr, e2w, dinv, H16, ntiles);
    prop_row<128, true><<<pb, 256, 0, stream>>>((const __half2*)H16, dinv, rowptr, colid, b_e2, A, 128, n);
    gemm_mfma<64, 128, 128><<<gb, 512, 0, stream>>>(A, nullptr, e3w, dinv, H16, ntiles);
    prop_row<64, false><<<pb, 256, 0, stream>>>((const __half2*)H16, dinv, rowptr, colid, b_e3, A, 64, n);

    // decoder (d1 reads z (ld=64) + condition directly; no condcopy)
    gemm_mfma<128, 96, 64><<<gb, 512, 0, stream>>>(A, condition, d1w, dinv, H16, ntiles);
    prop_row<128, true><<<pb, 256, 0, stream>>>((const __half2*)H16, dinv, rowptr, colid, b_d1, A, 128, n);
    gemm_mfma<128, 128, 128><<<gb, 512, 0, stream>>>(A, nullptr, d2w, dinv, H16, ntiles);
    prop_row<128, true><<<pb, 256, 0, stream>>>((const __half2*)H16, dinv, rowptr, colid, b_d2, A, 128, n);
    gemm_mfma<128, 128, 128><<<gb, 512, 0, stream>>>(A, nullptr, d3w, dinv, H16, ntiles);
    prop_row<128, false><<<pb, 256, 0, stream>>>((const __half2*)H16, dinv, rowptr, colid, b_d3, out, 128, n);
}

// Round 8
// 669.365 us; speedup vs baseline: 1.7798x; 1.0327x over previous
//
#include <hip/hip_runtime.h>
#include <hip/hip_fp16.h>
#include <math.h>

#define NN 100000
#define NE 1600000
#define NB ((NN + 255) >> 8)   // 391 buckets of 256 nodes
#define CHUNK 8192
#define CAP 8192

typedef __attribute__((ext_vector_type(4))) float floatx4;
typedef __attribute__((ext_vector_type(8))) short shortx8;

// ---------------- bucketed CSR build ----------------

__global__ __launch_bounds__(256)
void coarse_hist(const int* __restrict__ ei, int* __restrict__ bucket_cnt, int E) {
    __shared__ int h[512];
    int t = threadIdx.x;
    for (int i = t; i < 512; i += 256) h[i] = 0;
    __syncthreads();
    int base = blockIdx.x * CHUNK;
    int lim = min(base + CHUNK, E);
    for (int e = base + t; e < lim; e += 256) {
        int d = ei[E + e];
        atomicAdd(&h[d >> 8], 1);
    }
    __syncthreads();
    for (int i = t; i < 512; i += 256)
        if (h[i]) atomicAdd(&bucket_cnt[i], h[i]);
}

__global__ void scan_buckets(const int* __restrict__ bucket_cnt,
                             int* __restrict__ bucket_base,
                             int* __restrict__ bucket_fill) {
    __shared__ int sh[512];
    int t = threadIdx.x;  // 512 threads
    int v = (t < NB) ? bucket_cnt[t] : 0;
    sh[t] = v;
    __syncthreads();
    for (int off = 1; off < 512; off <<= 1) {
        int u = (t >= off) ? sh[t - off] : 0;
        __syncthreads();
        sh[t] += u;
        __syncthreads();
    }
    int ex = (t == 0) ? 0 : sh[t - 1];
    if (t <= NB) bucket_base[t] = ex;
    if (t < NB) bucket_fill[t] = ex;
}

__global__ __launch_bounds__(256)
void coarse_scatter(const int* __restrict__ ei, int* __restrict__ bucket_fill,
                    unsigned long long* __restrict__ pairs, int E) {
    __shared__ int h[512];
    __shared__ int base[512];
    int t = threadIdx.x;
    for (int i = t; i < 512; i += 256) h[i] = 0;
    __syncthreads();
    int cbase = blockIdx.x * CHUNK;
    int lim = min(cbase + CHUNK, E);
    for (int e = cbase + t; e < lim; e += 256) {
        int d = ei[E + e];
        atomicAdd(&h[d >> 8], 1);
    }
    __syncthreads();
    for (int i = t; i < 512; i += 256)
        base[i] = h[i] ? atomicAdd(&bucket_fill[i], h[i]) : 0;
    __syncthreads();
    for (int i = t; i < 512; i += 256) h[i] = 0;
    __syncthreads();
    for (int e = cbase + t; e < lim; e += 256) {
        int s = ei[e];
        int d = ei[E + e];
        int b = d >> 8;
        int r = atomicAdd(&h[b], 1);
        pairs[base[b] + r] =
            ((unsigned long long)(unsigned)d << 32) | (unsigned)s;
    }
}

__global__ __launch_bounds__(256)
void fine_csr(const unsigned long long* __restrict__ pairs,
              const int* __restrict__ bucket_base,
              int* __restrict__ rowptr, int* __restrict__ colid,
              float* __restrict__ dinv, int n) {
    __shared__ int hist[256];
    __shared__ int offs[256];
    __shared__ int rank[256];
    __shared__ int lbuf[CAP];
    int b = blockIdx.x, t = threadIdx.x;
    int beg = bucket_base[b], end = bucket_base[b + 1];
    int cnt = end - beg;
    hist[t] = 0; rank[t] = 0;
    __syncthreads();
    for (int i = t; i < cnt; i += 256) {
        int d = (int)(pairs[beg + i] >> 32);
        atomicAdd(&hist[d & 255], 1);
    }
    __syncthreads();
    int v = hist[t];
    offs[t] = v;
    __syncthreads();
    for (int off = 1; off < 256; off <<= 1) {
        int u = (t >= off) ? offs[t - off] : 0;
        __syncthreads();
        offs[t] += u;
        __syncthreads();
    }
    int ex = (t == 0) ? 0 : offs[t - 1];
    int node = (b << 8) + t;
    if (node < n) {
        rowptr[node] = beg + ex;
        dinv[node] = rsqrtf((float)v + 1.0f);
    } else if (node == n) {
        rowptr[n] = beg + ex;
    }
    __syncthreads();
    offs[t] = ex;
    __syncthreads();
    for (int i = t; i < cnt; i += 256) {
        unsigned long long p = pairs[beg + i];
        int d = (int)(p >> 32) & 255;
        int s = (int)(p & 0xffffffffu);
        int r = atomicAdd(&rank[d], 1);
        lbuf[offs[d] + r] = s;
    }
    __syncthreads();
    for (int i = t; i < cnt; i += 256) colid[beg + i] = lbuf[i];
}

// ---------------- weight prep: W[K][OUT] fp32 -> swizzled bf16 hi/lo fragments ----

__device__ __forceinline__ void wsplit_one(const float* __restrict__ W,
                                           unsigned short* __restrict__ Wsw,
                                           int i, int K, int OUT) {
    int k = i / OUT, o = i % OUT;
    float w = W[i];
    unsigned u = __float_as_uint(w);
    float r = w - __uint_as_float(u & 0xFFFF0000u);
    int NT = OUT >> 4;
    int ktc = k >> 5, q = (k >> 3) & 3, j = k & 7;
    int nt = o >> 4, mm = o & 15;
    int lane = (q << 4) | mm;
    size_t base = ((((size_t)(ktc * NT + nt) * 2) * 64 + lane) << 3) + j;
    Wsw[base] = (unsigned short)(u >> 16);
    Wsw[base + 512] = (unsigned short)(__float_as_uint(r) >> 16);  // h=1: +64*8
}

__global__ __launch_bounds__(256)
void wsplit_all(const float* __restrict__ W0, unsigned short* __restrict__ O0,
                const float* __restrict__ W1, unsigned short* __restrict__ O1,
                const float* __restrict__ W2, unsigned short* __restrict__ O2,
                const float* __restrict__ W3, unsigned short* __restrict__ O3,
                const float* __restrict__ W4, unsigned short* __restrict__ O4,
                const float* __restrict__ W5, unsigned short* __restrict__ O5) {
    int i = blockIdx.x * 256 + threadIdx.x;
    if (i < 20480) { wsplit_one(W0, O0, i, 160, 128); return; }
    i -= 20480;
    if (i < 16384) { wsplit_one(W1, O1, i, 128, 128); return; }
    i -= 16384;
    if (i < 8192)  { wsplit_one(W2, O2, i, 128, 64);  return; }
    i -= 8192;
    if (i < 12288) { wsplit_one(W3, O3, i, 96, 128);  return; }
    i -= 12288;
    if (i < 16384) { wsplit_one(W4, O4, i, 128, 128); return; }
    i -= 16384;
    if (i < 16384) { wsplit_one(W5, O5, i, 128, 128); }
}

// ---------------- standalone MFMA GEMM (layer e1 only) ------------------------
// r7 v3: 512 thr, 8 waves x 2 row-tiles (proven). fp32 inputs + split8.

__device__ __forceinline__ void split8(const float* v, shortx8& hi, shortx8& lo) {
#pragma unroll
    for (int i = 0; i < 8; i++) {
        unsigned u = __float_as_uint(v[i]);
        float r = v[i] - __uint_as_float(u & 0xFFFF0000u);
        hi[i] = (short)(u >> 16);
        lo[i] = (short)(__float_as_uint(r) >> 16);
    }
}

template <int OUT, int K, int K1>
__global__ __launch_bounds__(512, 4)
void gemm_mfma(const float* __restrict__ X1, const float* __restrict__ X2,
               const unsigned short* __restrict__ Wsw,
               const float* __restrict__ dinv,
               __half* __restrict__ Y, int ntiles) {
    constexpr int NT = OUT / 16;
    constexpr int NKTC = K / 32;
    constexpr int K2 = K - K1;
    constexpr int PERC = OUT * 128;
    constexpr int CSZ = (65536 / PERC < NKTC) ? (65536 / PERC) : NKTC;
    __shared__ __align__(16) unsigned short lds[CSZ * PERC / 2];

    const int t = threadIdx.x;
    const int wave = t >> 6, lane = t & 63;
    const int m = lane & 15, q = lane >> 4;
    const int tile0 = blockIdx.x * 16 + wave * 2;
    const int tile1 = tile0 + 1;
    const bool act0 = tile0 < ntiles;
    const bool act1 = tile1 < ntiles;
    const int r0 = act0 ? tile0 * 16 + m : 0;
    const int r1 = act1 ? tile1 * 16 + m : 0;
    const float* ap1a = X1 + (size_t)r0 * K1 + q * 8;
    const float* ap1b = X1 + (size_t)r1 * K1 + q * 8;
    const float* ap2a = (K2 > 0) ? (X2 + (size_t)r0 * K2 + q * 8) : X1;
    const float* ap2b = (K2 > 0) ? (X2 + (size_t)r1 * K2 + q * 8) : X1;

    floatx4 acc0[NT], acc1[NT];
#pragma unroll
    for (int nt = 0; nt < NT; nt++) {
        acc0[nt] = (floatx4){0.f, 0.f, 0.f, 0.f};
        acc1[nt] = (floatx4){0.f, 0.f, 0.f, 0.f};
    }

#pragma unroll
    for (int c0 = 0; c0 < NKTC; c0 += CSZ) {
        const int cl = (NKTC - c0 < CSZ) ? (NKTC - c0) : CSZ;
        if (c0 != 0) __syncthreads();
        {
            const float4* gs = (const float4*)Wsw + (size_t)c0 * (PERC / 16);
            float4* ld = (float4*)lds;
            int tot = cl * (PERC / 16);
            for (int i = t; i < tot; i += 512) ld[i] = gs[i];
        }
        __syncthreads();
#pragma unroll
        for (int ktc = 0; ktc < cl; ktc++) {
            const int kg = (c0 + ktc) * 32;
            const float* pa = (kg < K1) ? (ap1a + kg) : (ap2a + (kg - K1));
            const float* pb = (kg < K1) ? (ap1b + kg) : (ap2b + (kg - K1));
            float av0[8], av1[8];
            *(float4*)&av0[0] = *(const float4*)(pa);
            *(float4*)&av0[4] = *(const float4*)(pa + 4);
            *(float4*)&av1[0] = *(const float4*)(pb);
            *(float4*)&av1[4] = *(const float4*)(pb + 4);
            shortx8 ahi0, alo0, ahi1, alo1;
            split8(av0, ahi0, alo0);
            split8(av1, ahi1, alo1);
#pragma unroll
            for (int nt = 0; nt < NT; nt++) {
                const unsigned short* fb =
                    lds + ((((ktc * NT + nt) * 2) * 64 + lane) << 3);
                shortx8 bhi = *(const shortx8*)fb;
                shortx8 blo = *(const shortx8*)(fb + 512);
                acc0[nt] = __builtin_amdgcn_mfma_f32_16x16x32_bf16(ahi0, bhi, acc0[nt], 0, 0, 0);
                acc1[nt] = __builtin_amdgcn_mfma_f32_16x16x32_bf16(ahi1, bhi, acc1[nt], 0, 0, 0);
                acc0[nt] = __builtin_amdgcn_mfma_f32_16x16x32_bf16(ahi0, blo, acc0[nt], 0, 0, 0);
                acc1[nt] = __builtin_amdgcn_mfma_f32_16x16x32_bf16(ahi1, blo, acc1[nt], 0, 0, 0);
                acc0[nt] = __builtin_amdgcn_mfma_f32_16x16x32_bf16(alo0, bhi, acc0[nt], 0, 0, 0);
                acc1[nt] = __builtin_amdgcn_mfma_f32_16x16x32_bf16(alo1, bhi, acc1[nt], 0, 0, 0);
            }
        }
    }

    if (act0) {
        float di[4];
#pragma unroll
        for (int r = 0; r < 4; r++) di[r] = dinv[tile0 * 16 + q * 4 + r];
#pragma unroll
        for (int nt = 0; nt < NT; nt++)
#pragma unroll
            for (int r = 0; r < 4; r++) {
                int orow = tile0 * 16 + q * 4 + r;
                Y[(size_t)orow * OUT + nt * 16 + m] =
                    __float2half_rn(acc0[nt][r] * di[r]);
            }
    }
    if (act1) {
        float di[4];
#pragma unroll
        for (int r = 0; r < 4; r++) di[r] = dinv[tile1 * 16 + q * 4 + r];
#pragma unroll
        for (int nt = 0; nt < NT; nt++)
#pragma unroll
            for (int r = 0; r < 4; r++) {
                int orow = tile1 * 16 + q * 4 + r;
                Y[(size_t)orow * OUT + nt * 16 + m] =
                    __float2half_rn(acc1[nt][r] * di[r]);
            }
    }
}

// ---------------- FUSED prop(i) + GEMM(i+1) ----------------------------------
// Block = 16 nodes (one GEMM row-tile), 4 waves.
// Phase 1 (verbatim prop_row inner loop): wave w gathers nodes w*4..w*4+3 from
//   hin (pre-scaled fp16), applies dinv+bias(+tanh), splits to bf16 hi/lo and
//   stores the X tile [16][KG] in LDS (XOR-swizzled, G4 bank fix).
//   CC variant appends condition (fp32->hi/lo) as cols 64..95.
// Phase 2 (verbatim MFMA fragment loop): A-frags from LDS (swizzled read),
//   W hi/lo frags straight from global (64 KB, L2-resident; no LDS staging),
//   triple-MFMA bf16 split, epilogue scales by dinv[row] -> hout fp16.
// MFMA math is ~4 us/layer; its staging latency hides under other resident
// blocks' gather phases (4 blocks/CU) -> layer time ~ gather time.

template <int INW, int OUT, bool CC, bool TANH>
__global__ __launch_bounds__(256, 4)
void fused_pg(const __half2* __restrict__ hin, const float* __restrict__ dinv,
              const int* __restrict__ rowptr, const int* __restrict__ colid,
              const float* __restrict__ biasIn, const float* __restrict__ cond,
              const unsigned short* __restrict__ Wsw,
              __half* __restrict__ hout, int n) {
    constexpr int KG = CC ? INW + 32 : INW;   // GEMM K
    constexpr int NT = OUT / 16;
    constexpr int NTW = NT / 4;               // col-tiles per wave
    constexpr int NKTC = KG / 32;
    constexpr int LPR = INW / 4;              // lanes per row in gather
    constexpr int G = 64 / LPR;               // edge groups
    constexpr int RS2 = INW / 4;              // float2 per row

    __shared__ __align__(16) unsigned char xlds[8192];  // hi[16][128] + lo[16][128] bf16

    const int t = threadIdx.x;
    const int wave = t >> 6, lane = t & 63;
    const int blk = blockIdx.x;
    const int g = lane / LPR, fq = lane % LPR;
    const float2* __restrict__ b2 = (const float2*)hin;

    // ---- phase 1: gather 4 nodes per wave ----
    for (int nd = 0; nd < 4; nd++) {
        int node = blk * 16 + wave * 4 + nd;
        int beg = rowptr[node], end = rowptr[node + 1];
        float ax = 0.f, ay = 0.f, az = 0.f, aw = 0.f;
        int e = beg;
        for (; e + 8 * G <= end; e += 8 * G) {
            int s[8];
#pragma unroll
            for (int j = 0; j < 8; j++) s[j] = colid[e + j * G + g];
            float2 v[8];
#pragma unroll
            for (int j = 0; j < 8; j++) v[j] = b2[(size_t)s[j] * RS2 + fq];
#pragma unroll
            for (int j = 0; j < 8; j++) {
                float2 f0 = __half22float2(*(const __half2*)&v[j].x);
                float2 f1 = __half22float2(*(const __half2*)&v[j].y);
                ax += f0.x; ay += f0.y; az += f1.x; aw += f1.y;
            }
        }
        if (e + 4 * G <= end) {
            int s[4];
#pragma unroll
            for (int j = 0; j < 4; j++) s[j] = colid[e + j * G + g];
            float2 v[4];
#pragma unroll
            for (int j = 0; j < 4; j++) v[j] = b2[(size_t)s[j] * RS2 + fq];
#pragma unroll
            for (int j = 0; j < 4; j++) {
                float2 f0 = __half22float2(*(const __half2*)&v[j].x);
                float2 f1 = __half22float2(*(const __half2*)&v[j].y);
                ax += f0.x; ay += f0.y; az += f1.x; aw += f1.y;
            }
            e += 4 * G;
        }
        for (; e + G <= end; e += G) {
            int s = colid[e + g];
            float2 v = b2[(size_t)s * RS2 + fq];
            float2 f0 = __half22float2(*(const __half2*)&v.x);
            float2 f1 = __half22float2(*(const __half2*)&v.y);
            ax += f0.x; ay += f0.y; az += f1.x; aw += f1.y;
        }
        if (e + g < end) {
            int s = colid[e + g];
            float2 v = b2[(size_t)s * RS2 + fq];
            float2 f0 = __half22float2(*(const __half2*)&v.x);
            float2 f1 = __half22float2(*(const __half2*)&v.y);
            ax += f0.x; ay += f0.y; az += f1.x; aw += f1.y;
        }
        if constexpr (G >= 2) {
            ax += __shfl_xor(ax, LPR); ay += __shfl_xor(ay, LPR);
            az += __shfl_xor(az, LPR); aw += __shfl_xor(aw, LPR);
        }
        if constexpr (G == 4) {
            ax += __shfl_xor(ax, 2 * LPR); ay += __shfl_xor(ay, 2 * LPR);
            az += __shfl_xor(az, 2 * LPR); aw += __shfl_xor(aw, 2 * LPR);
        }
        const int r = wave * 4 + nd;
        if (g == 0) {
            float2 sv = b2[(size_t)node * RS2 + fq];
            float2 f0 = __half22float2(*(const __half2*)&sv.x);
            float2 f1 = __half22float2(*(const __half2*)&sv.y);
            ax += f0.x; ay += f0.y; az += f1.x; aw += f1.y;
            float di = dinv[node];
            float4 bb = *(const float4*)(biasIn + fq * 4);
            float o0 = di * ax + bb.x;
            float o1 = di * ay + bb.y;
            float o2 = di * az + bb.z;
            float o3 = di * aw + bb.w;
            if (TANH) { o0 = tanhf(o0); o1 = tanhf(o1); o2 = tanhf(o2); o3 = tanhf(o3); }
            float o[4] = {o0, o1, o2, o3};
            unsigned short hi[4], lo[4];
#pragma unroll
            for (int i = 0; i < 4; i++) {
                unsigned u = __float_as_uint(o[i]);
                float rr = o[i] - __uint_as_float(u & 0xFFFF0000u);
                hi[i] = (unsigned short)(u >> 16);
                lo[i] = (unsigned short)(__float_as_uint(rr) >> 16);
            }
            int off = (r * 256 + fq * 8) ^ ((r & 7) << 4);
            *(uint2*)(xlds + off) = *(const uint2*)hi;
            *(uint2*)(xlds + 4096 + off) = *(const uint2*)lo;
        }
        if constexpr (CC) {
            if (g == 1 && fq < 8) {
                float4 cv = ((const float4*)cond)[(size_t)node * 8 + fq];
                float c[4] = {cv.x, cv.y, cv.z, cv.w};
                unsigned short hi[4], lo[4];
#pragma unroll
                for (int i = 0; i < 4; i++) {
                    unsigned u = __float_as_uint(c[i]);
                    float rr = c[i] - __uint_as_float(u & 0xFFFF0000u);
                    hi[i] = (unsigned short)(u >> 16);
                    lo[i] = (unsigned short)(__float_as_uint(rr) >> 16);
                }
                int off = (r * 256 + 128 + fq * 8) ^ ((r & 7) << 4);
                *(uint2*)(xlds + off) = *(const uint2*)hi;
                *(uint2*)(xlds + 4096 + off) = *(const uint2*)lo;
            }
        }
    }
    __syncthreads();

    // ---- phase 2: GEMM 16 x KG @ KG x OUT ----
    const int m = lane & 15, q = lane >> 4;
    floatx4 acc[NTW];
#pragma unroll
    for (int j = 0; j < NTW; j++) acc[j] = (floatx4){0.f, 0.f, 0.f, 0.f};

#pragma unroll
    for (int kc = 0; kc < NKTC; kc++) {
        int rdoff = (m * 256 + kc * 64 + q * 16) ^ ((m & 7) << 4);
        shortx8 ahi = *(const shortx8*)(xlds + rdoff);
        shortx8 alo = *(const shortx8*)(xlds + 4096 + rdoff);
#pragma unroll
        for (int j = 0; j < NTW; j++) {
            int nt = wave * NTW + j;
            const unsigned short* wp =
                Wsw + ((((size_t)(kc * NT + nt) * 2) * 64 + lane) << 3);
            shortx8 whi = *(const shortx8*)wp;
            shortx8 wlo = *(const shortx8*)(wp + 512);
            acc[j] = __builtin_amdgcn_mfma_f32_16x16x32_bf16(ahi, whi, acc[j], 0, 0, 0);
            acc[j] = __builtin_amdgcn_mfma_f32_16x16x32_bf16(ahi, wlo, acc[j], 0, 0, 0);
            acc[j] = __builtin_amdgcn_mfma_f32_16x16x32_bf16(alo, whi, acc[j], 0, 0, 0);
        }
    }

    float di[4];
#pragma unroll
    for (int r = 0; r < 4; r++) di[r] = dinv[blk * 16 + q * 4 + r];
#pragma unroll
    for (int j = 0; j < NTW; j++) {
        int nt = wave * NTW + j;
#pragma unroll
        for (int r = 0; r < 4; r++) {
            int orow = blk * 16 + q * 4 + r;
            hout[(size_t)orow * OUT + nt * 16 + m] =
                __float2half_rn(acc[j][r] * di[r]);
        }
    }
}

// ---------------- standalone propagation (layer d3 tail) ----------------------
// PROVEN config (rounds 3/6/7: 70.5-71.2 us, 192 MB fetch = compulsory floor).

template <int OUT, bool TANH>
__global__ __launch_bounds__(256)
void prop_row(const __half2* __restrict__ hs, const float* __restrict__ dinv,
              const int* __restrict__ rowptr, const int* __restrict__ colid,
              const float* __restrict__ bias, float* __restrict__ out,
              int ldo, int n) {
    constexpr int LPR = OUT / 4;
    constexpr int G = 64 / LPR;
    constexpr int RS2 = OUT / 4;

    int wave = threadIdx.x >> 6, lane = threadIdx.x & 63;
    int node = blockIdx.x * 4 + wave;
    if (node >= n) return;
    int g = lane / LPR, fq = lane % LPR;
    int beg = rowptr[node], end = rowptr[node + 1];
    const float2* __restrict__ b2 = (const float2*)hs;

    float ax = 0.f, ay = 0.f, az = 0.f, aw = 0.f;
    int e = beg;
    for (; e + 8 * G <= end; e += 8 * G) {
        int s[8];
#pragma unroll
        for (int j = 0; j < 8; j++) s[j] = colid[e + j * G + g];
        float2 v[8];
#pragma unroll
        for (int j = 0; j < 8; j++) v[j] = b2[(size_t)s[j] * RS2 + fq];
#pragma unroll
        for (int j = 0; j < 8; j++) {
            float2 f0 = __half22float2(*(const __half2*)&v[j].x);
            float2 f1 = __half22float2(*(const __half2*)&v[j].y);
            ax += f0.x; ay += f0.y; az += f1.x; aw += f1.y;
        }
    }
    if (e + 4 * G <= end) {
        int s[4];
#pragma unroll
        for (int j = 0; j < 4; j++) s[j] = colid[e + j * G + g];
        float2 v[4];
#pragma unroll
        for (int j = 0; j < 4; j++) v[j] = b2[(size_t)s[j] * RS2 + fq];
#pragma unroll
        for (int j = 0; j < 4; j++) {
            float2 f0 = __half22float2(*(const __half2*)&v[j].x);
            float2 f1 = __half22float2(*(const __half2*)&v[j].y);
            ax += f0.x; ay += f0.y; az += f1.x; aw += f1.y;
        }
        e += 4 * G;
    }
    for (; e + G <= end; e += G) {
        int s = colid[e + g];
        float2 v = b2[(size_t)s * RS2 + fq];
        float2 f0 = __half22float2(*(const __half2*)&v.x);
        float2 f1 = __half22float2(*(const __half2*)&v.y);
        ax += f0.x; ay += f0.y; az += f1.x; aw += f1.y;
    }
    if (e + g < end) {
        int s = colid[e + g];
        float2 v = b2[(size_t)s * RS2 + fq];
        float2 f0 = __half22float2(*(const __half2*)&v.x);
        float2 f1 = __half22float2(*(const __half2*)&v.y);
        ax += f0.x; ay += f0.y; az += f1.x; aw += f1.y;
    }

    if constexpr (G >= 2) {
        ax += __shfl_xor(ax, LPR); ay += __shfl_xor(ay, LPR);
        az += __shfl_xor(az, LPR); aw += __shfl_xor(aw, LPR);
    }
    if constexpr (G == 4) {
        ax += __shfl_xor(ax, 2 * LPR); ay += __shfl_xor(ay, 2 * LPR);
        az += __shfl_xor(az, 2 * LPR); aw += __shfl_xor(aw, 2 * LPR);
    }

    if (g == 0) {
        float2 sv = b2[(size_t)node * RS2 + fq];
        float2 f0 = __half22float2(*(const __half2*)&sv.x);
        float2 f1 = __half22float2(*(const __half2*)&sv.y);
        ax += f0.x; ay += f0.y; az += f1.x; aw += f1.y;
        float di = dinv[node];
        float4 bb = *(const float4*)(bias + fq * 4);
        float ox = di * ax + bb.x;
        float oy = di * ay + bb.y;
        float oz = di * az + bb.z;
        float ow = di * aw + bb.w;
        if (TANH) { ox = tanhf(ox); oy = tanhf(oy); oz = tanhf(oz); ow = tanhf(ow); }
        *(float4*)(out + (size_t)node * ldo + fq * 4) = make_float4(ox, oy, oz, ow);
    }
}

// ---------------- launch ----------------

extern "C" void kernel_launch(void* const* d_in, const int* in_sizes, int n_in,
                              void* d_out, int out_size, void* d_ws, size_t ws_size,
                              hipStream_t stream) {
    const int n = NN, E = NE;
    const float* feature   = (const float*)d_in[0];
    const float* condition = (const float*)d_in[1];
    const int*   ei        = (const int*)d_in[2];
    const float* W_e1 = (const float*)d_in[3];  const float* b_e1 = (const float*)d_in[4];
    const float* W_e2 = (const float*)d_in[5];  const float* b_e2 = (const float*)d_in[6];
    const float* W_e3 = (const float*)d_in[7];  const float* b_e3 = (const float*)d_in[8];
    const float* W_d1 = (const float*)d_in[9];  const float* b_d1 = (const float*)d_in[10];
    const float* W_d2 = (const float*)d_in[11]; const float* b_d2 = (const float*)d_in[12];
    const float* W_d3 = (const float*)d_in[13]; const float* b_d3 = (const float*)d_in[14];
    float* out = (float*)d_out;

    float*  A    = (float*)d_ws;                    // n*160 floats (H16b lives here now)
    __half* H16a = (__half*)(A + (size_t)n * 160);  // n*128 halves
    __half* H16b = (__half*)A;                      // n*128 halves (reuses A slot)
    float*  dinv = (float*)(H16a + (size_t)n * 128); // n
    int* rowptr  = (int*)(dinv + n);                // n+1
    int* colid   = rowptr + n + 1;                  // E
    uintptr_t pp = (uintptr_t)(colid + E);
    pp = (pp + 15) & ~(uintptr_t)15;
    unsigned long long* pairs = (unsigned long long*)pp;  // E
    int* bucket_cnt  = (int*)(pairs + E);           // 512
    int* bucket_base = bucket_cnt + 512;            // 512
    int* bucket_fill = bucket_base + 512;           // 512
    uintptr_t wp = (uintptr_t)(bucket_fill + 512);
    wp = (wp + 15) & ~(uintptr_t)15;
    unsigned short* wt = (unsigned short*)wp;
    unsigned short* e1w = wt;              unsigned short* e2w = e1w + 160 * 128 * 2;
    unsigned short* e3w = e2w + 128*128*2; unsigned short* d1w = e3w + 128 * 64 * 2;
    unsigned short* d2w = d1w + 96*128*2;  unsigned short* d3w = d2w + 128 * 128 * 2;

    hipMemsetAsync(bucket_cnt, 0, 512 * sizeof(int), stream);

    int nbc = (E + CHUNK - 1) / CHUNK;
    coarse_hist<<<nbc, 256, 0, stream>>>(ei, bucket_cnt, E);
    scan_buckets<<<1, 512, 0, stream>>>(bucket_cnt, bucket_base, bucket_fill);
    coarse_scatter<<<nbc, 256, 0, stream>>>(ei, bucket_fill, pairs, E);
    fine_csr<<<NB, 256, 0, stream>>>(pairs, bucket_base, rowptr, colid, dinv, n);

    wsplit_all<<<(90112 + 255) / 256, 256, 0, stream>>>(
        W_e1, e1w, W_e2, e2w, W_e3, e3w, W_d1, d1w, W_d2, d2w, W_d3, d3w);

    const int ntiles = n / 16;          // 6250 exactly
    const int gb = (ntiles + 15) / 16;  // 391 blocks for standalone e1 GEMM
    const int fb = ntiles;              // 6250 fused blocks (16 nodes each)
    const int pb = (n + 3) / 4;         // 25000 blocks for tail prop

    // head: e1 GEMM (feature+condition fp32 -> H16a)
    gemm_mfma<128, 160, 128><<<gb, 512, 0, stream>>>(feature, condition, e1w, dinv, H16a, ntiles);
    // fused prop(e1)+gemm(e2): H16a -> H16b
    fused_pg<128, 128, false, true><<<fb, 256, 0, stream>>>(
        (const __half2*)H16a, dinv, rowptr, colid, b_e1, nullptr, e2w, H16b, n);
    // fused prop(e2)+gemm(e3): H16b -> H16a (n x 64)
    fused_pg<128, 64, false, true><<<fb, 256, 0, stream>>>(
        (const __half2*)H16b, dinv, rowptr, colid, b_e2, nullptr, e3w, H16a, n);
    // fused prop(e3, no tanh)+concat(cond)+gemm(d1): H16a(64) -> H16b
    fused_pg<64, 128, true, false><<<fb, 256, 0, stream>>>(
        (const __half2*)H16a, dinv, rowptr, colid, b_e3, condition, d1w, H16b, n);
    // fused prop(d1)+gemm(d2): H16b -> H16a
    fused_pg<128, 128, false, true><<<fb, 256, 0, stream>>>(
        (const __half2*)H16b, dinv, rowptr, colid, b_d1, nullptr, d2w, H16a, n);
    // fused prop(d2)+gemm(d3): H16a -> H16b
    fused_pg<128, 128, false, true><<<fb, 256, 0, stream>>>(
        (const __half2*)H16a, dinv, rowptr, colid, b_d2, nullptr, d3w, H16b, n);
    // tail: prop(d3) -> out
    prop_row<128, false><<<pb, 256, 0, stream>>>(
        (const __half2*)H16b, dinv, rowptr, colid, b_d3, out, 128, n);
}